// Round 5
// baseline (107.529 us; speedup 1.0000x reference)
//
#include <hip/hip_runtime.h>

typedef int   v4i __attribute__((ext_vector_type(4)));
typedef float v4f __attribute__((ext_vector_type(4)));
typedef unsigned short ushort_t;

#define NB 32
#define CI 128
#define HW 56
#define KOC 256
#define HP 58
#define MTOT (NB*HW*HW)                  // 100352
#define XP_ELEMS ((size_t)NB*HP*HP*CI)   // 13778944
#define XP_OFF_BYTES ((size_t)1<<20)

__device__ __forceinline__ unsigned short f2bf(float f) {
    unsigned int u = __builtin_bit_cast(unsigned int, f);
    u += 0x7fffu + ((u >> 16) & 1u);   // round-to-nearest-even
    return (unsigned short)(u >> 16);
}

__device__ __forceinline__ void gload16(const void* g, void* l) {
    __builtin_amdgcn_global_load_lds(
        (const __attribute__((address_space(1))) void*)g,
        (__attribute__((address_space(3))) void*)l, 16, 0, 0);
}

// ---- weight (256,128,3,3) f32 -> Wb[rs][ko][c] bf16 (c contiguous)
__global__ void wt_bf16(const float* __restrict__ w, ushort_t* __restrict__ wb) {
    int t = blockIdx.x * 256 + threadIdx.x;      // t = ko*128 + c
    if (t >= KOC * CI) return;
    const float* src = w + (size_t)t * 9;
    int ko = t >> 7, c = t & 127;
    #pragma unroll
    for (int rs = 0; rs < 9; ++rs)
        wb[(size_t)(rs * KOC + ko) * CI + c] = f2bf(src[rs]);
}

// ---- x NCHW f32 -> padded NHWC bf16 Xp[n][58][58][128] (interior only)
__global__ void pad_nhwc_bf16(const float* __restrict__ x, ushort_t* __restrict__ xp) {
    __shared__ ushort_t tile[HW][136];
    int b = blockIdx.x;                          // n*56 + h
    int n = b / HW, h = b % HW;
    int tid = threadIdx.x;
    const float* xr = x + (size_t)n * CI * HW * HW + (size_t)h * HW;
    for (int idx = tid; idx < CI * HW; idx += 256) {
        int c = idx / HW, w = idx % HW;
        tile[w][c] = f2bf(xr[(size_t)c * (HW * HW) + w]);
    }
    __syncthreads();
    ushort_t* xpr = xp + ((size_t)(n * HP + (h + 1)) * HP + 1) * CI;
    for (int idx = tid; idx < (HW * CI) / 8; idx += 256) {
        int w = idx >> 4, c8 = (idx & 15) * 8;
        *reinterpret_cast<uint4*>(xpr + (size_t)w * CI + c8) =
            *reinterpret_cast<const uint4*>(&tile[w][c8]);
    }
}

// ---- zero only the padding border of Xp
__global__ void border_zero(ushort_t* __restrict__ xp) {
    int t = blockIdx.x * 256 + threadIdx.x;
    if (t >= NB * 228 * 16) return;
    int c16 = t & 15;
    int p = (t >> 4) % 228;
    int n = t / (228 * 16);
    int h, wc;
    if (p < 58)       { h = 0;               wc = p; }
    else if (p < 116) { h = 57;              wc = p - 58; }
    else { int q = p - 116; h = 1 + (q >> 1); wc = (q & 1) * 57; }
    size_t off = ((size_t)(n * HP + h) * HP + wc) * CI + (size_t)c16 * 8;
    uint4 z; z.x = z.y = z.z = z.w = 0u;
    *reinterpret_cast<uint4*>(xp + off) = z;
}

// ================= main conv: 256x256 tile, 8-phase, builtin barriers ===========
// A = W (ko rows), B = X (m rows). 8 waves: 2(ko-half 128) x 4(m-quarter 64).
// Planes sA/sB[buf][kh][256 rows x 32 elems]; 2 bufs = 128 KB total.
// Stage event = one plane = 2 gload16/thread. Swizzle: slot = chunk ^ ((row>>1)&3).
// KEY vs R4: __builtin_amdgcn_s_barrier (NOT asm+"memory" clobber -> no full
// vmcnt drain per phase), clobber-free counted vmcnt, sched_barrier(0) fence.

#define BAR()  __builtin_amdgcn_s_barrier()
#define SCHB() __builtin_amdgcn_sched_barrier(0)
#define VMW(n) asm volatile("s_waitcnt vmcnt(" #n ")")
#define NOVM() ((void)0)

#define PHASE(BUF, KH, MH, STAGE_STMT, VMSTMT) do {                               \
    if ((MH) == 0) {                                                              \
        _Pragma("unroll")                                                         \
        for (int a = 0; a < 8; ++a)                                               \
            af[a] = *reinterpret_cast<const v4i*>(&sA[BUF][KH][aoffE[a]]);        \
    }                                                                             \
    v4i bf0 = *reinterpret_cast<const v4i*>(&sB[BUF][KH][boffE[(MH)*2]]);         \
    v4i bf1 = *reinterpret_cast<const v4i*>(&sB[BUF][KH][boffE[(MH)*2+1]]);       \
    STAGE_STMT;                                                                   \
    VMSTMT;                                                                       \
    BAR();                                                                        \
    SCHB();                                                                       \
    __builtin_amdgcn_s_setprio(1);                                                \
    _Pragma("unroll")                                                             \
    for (int a = 0; a < 8; ++a) {                                                 \
        asm volatile("v_mfma_f32_16x16x32_bf16 %0, %1, %2, %0"                    \
                     : "+v"(acc[a][(MH)*2])   : "v"(af[a]), "v"(bf0));            \
        asm volatile("v_mfma_f32_16x16x32_bf16 %0, %1, %2, %0"                    \
                     : "+v"(acc[a][(MH)*2+1]) : "v"(af[a]), "v"(bf1));            \
    }                                                                             \
    __builtin_amdgcn_s_setprio(0);                                                \
    BAR();                                                                        \
} while (0)

__global__ __launch_bounds__(512, 2) void conv_mfma(
    const ushort_t* __restrict__ xp,
    const ushort_t* __restrict__ wb,
    const float* __restrict__ bias,
    float* __restrict__ out)
{
    __shared__ alignas(16) ushort_t sA[2][2][8192];   // [buf][kh][256r x 32e]
    __shared__ alignas(16) ushort_t sB[2][2][8192];

    const int tid  = threadIdx.x;
    const int lane = tid & 63;
    const int wv   = tid >> 6;          // 0..7
    const int wko2 = wv >> 2;           // ko half (128 rows)
    const int wm4  = wv & 3;            // m quarter (64 rows)
    // XCD-aware bijective swizzle: 392 blocks = 8 XCDs x 49 contiguous chunks
    const int bid  = blockIdx.x;
    const int swz  = (bid & 7) * 49 + (bid >> 3);
    const int m0   = swz * 256;
    const int lm = lane & 15, lk = lane >> 4;

    // ---- staging sources (per thread): rows srow, srow+128; chunk swizzled
    const int srow = tid >> 2;                        // 0..127
    const int sc   = (tid & 3) ^ ((tid >> 3) & 3);    // inverse-swizzled chunk
    const size_t wA0 = (size_t)srow * CI + sc * 8;
    const size_t wA1 = (size_t)(srow + 128) * CI + sc * 8;
    size_t xB0, xB1;
    {
        int mm = m0 + srow;
        int n = mm / 3136, tt = mm % 3136, oh = tt / 56, ow = tt % 56;
        xB0 = ((size_t)(n * HP + oh) * HP + ow) * CI + sc * 8;
        mm = m0 + 128 + srow;
        n = mm / 3136; tt = mm % 3136; oh = tt / 56; ow = tt % 56;
        xB1 = ((size_t)(n * HP + oh) * HP + ow) * CI + sc * 8;
    }

    auto stageA = [&](int buf, int kh, int kt) {
        int rs = kt >> 1, ch = (kt & 1) << 6;
        size_t g = (size_t)rs * (KOC * CI) + ch + kh * 32;
        char* d = (char*)&sA[buf][kh][0] + wv * 1024;
        gload16(wb + wA0 + g, d);
        gload16(wb + wA1 + g, d + 8192);
    };
    auto stageB = [&](int buf, int kh, int kt) {
        int rs = kt >> 1, ch = (kt & 1) << 6;
        int r = (rs * 11) >> 5, s = rs - r * 3;
        size_t g = (size_t)(r * HP + s) * CI + ch + kh * 32;
        char* d = (char*)&sB[buf][kh][0] + wv * 1024;
        gload16(xp + xB0 + g, d);
        gload16(xp + xB1 + g, d + 8192);
    };

    // ---- fragment LDS offsets in ELEMENTS (within a plane)
    int aoffE[8], boffE[4];
    #pragma unroll
    for (int a = 0; a < 8; ++a) {
        int row = wko2 * 128 + a * 16 + lm;
        aoffE[a] = row * 32 + (lk ^ ((row >> 1) & 3)) * 8;
    }
    #pragma unroll
    for (int bb = 0; bb < 4; ++bb) {
        int row = wm4 * 64 + bb * 16 + lm;
        boffE[bb] = row * 32 + (lk ^ ((row >> 1) & 3)) * 8;
    }

    v4f acc[8][4];
    const v4f vzero = {0.f, 0.f, 0.f, 0.f};
    #pragma unroll
    for (int a = 0; a < 8; ++a)
        #pragma unroll
        for (int b = 0; b < 4; ++b) acc[a][b] = vzero;

    v4i af[8];

    // ---- prologue: tile0 both k-halves + tile1 k0 (6 events, 12 loads)
    stageA(0, 0, 0); stageB(0, 0, 0); stageA(0, 1, 0); stageB(0, 1, 0);
    stageA(1, 0, 1); stageB(1, 0, 1);
    VMW(4);          // retire tile0 planes; tile1-k0 still in flight
    BAR();

    // ---- main loop: iter t computes tiles 2t (buf0), 2t+1 (buf1)
    // counted vmcnt(4) ONLY at P4 and P8; never 0 in the main loop
    for (int t = 0; t < 8; ++t) {
        int e2 = 2 * t;
        PHASE(0, 0, 0, stageA(1, 1, e2 + 1), NOVM());
        PHASE(0, 0, 1, stageB(1, 1, e2 + 1), NOVM());
        PHASE(0, 1, 0, stageA(0, 0, e2 + 2), NOVM());
        PHASE(0, 1, 1, stageB(0, 0, e2 + 2), VMW(4));
        PHASE(1, 0, 0, stageA(0, 1, e2 + 2), NOVM());
        PHASE(1, 0, 1, stageB(0, 1, e2 + 2), NOVM());
        PHASE(1, 1, 0, stageA(1, 0, e2 + 3), NOVM());
        PHASE(1, 1, 1, stageB(1, 0, e2 + 3), VMW(4));
    }

    // ---- peeled final iter: tiles 16 (buf0), 17 (buf1)
    PHASE(0, 0, 0, stageA(1, 1, 17), NOVM());
    PHASE(0, 0, 1, stageB(1, 1, 17), NOVM());
    PHASE(0, 1, 0, NOVM(), NOVM());
    PHASE(0, 1, 1, NOVM(), VMW(2));   // retires through tile17-k0 planes
    PHASE(1, 0, 0, NOVM(), NOVM());
    PHASE(1, 0, 1, NOVM(), VMW(0));   // retires tile17-k1 planes
    PHASE(1, 1, 0, NOVM(), NOVM());
    PHASE(1, 1, 1, NOVM(), NOVM());

    // ---- MFMA->VALU hazard fence (asm MFMAs: compiler doesn't add hazard nops)
    asm volatile("s_nop 7\n\ts_nop 7"
        : "+v"(acc[0][0]), "+v"(acc[0][1]), "+v"(acc[0][2]), "+v"(acc[0][3]),
          "+v"(acc[1][0]), "+v"(acc[1][1]), "+v"(acc[1][2]), "+v"(acc[1][3]),
          "+v"(acc[2][0]), "+v"(acc[2][1]), "+v"(acc[2][2]), "+v"(acc[2][3]),
          "+v"(acc[3][0]), "+v"(acc[3][1]), "+v"(acc[3][2]), "+v"(acc[3][3]));
    asm volatile("s_nop 7\n\ts_nop 7"
        : "+v"(acc[4][0]), "+v"(acc[4][1]), "+v"(acc[4][2]), "+v"(acc[4][3]),
          "+v"(acc[5][0]), "+v"(acc[5][1]), "+v"(acc[5][2]), "+v"(acc[5][3]),
          "+v"(acc[6][0]), "+v"(acc[6][1]), "+v"(acc[6][2]), "+v"(acc[6][3]),
          "+v"(acc[7][0]), "+v"(acc[7][1]), "+v"(acc[7][2]), "+v"(acc[7][3]));

    // ---- epilogue: D row=(lane>>4)*4+r -> ko ; col=lane&15 -> m
    const int koB = wko2 * 128 + lk * 4;
    v4f bv[8];
    #pragma unroll
    for (int a = 0; a < 8; ++a)
        bv[a] = *reinterpret_cast<const v4f*>(bias + koB + a * 16);

    #pragma unroll
    for (int bb = 0; bb < 4; ++bb) {
        int mcol = m0 + wm4 * 64 + bb * 16 + lm;
        int n = mcol / 3136, t4 = mcol % 3136, oh = t4 / 56, ow = t4 % 56;
        size_t obase = (size_t)n * (KOC * 3136) + (size_t)oh * 56 + ow;
        #pragma unroll
        for (int a = 0; a < 8; ++a) {
            int kk = koB + a * 16;
            #pragma unroll
            for (int r = 0; r < 4; ++r)
                out[obase + (size_t)(kk + r) * 3136] = acc[a][bb][r] + bv[a][r];
        }
    }
}

// ---- insurance path if workspace is too small
__global__ void conv_naive(const float* __restrict__ x, const float* __restrict__ w,
                           const float* __restrict__ bias, float* __restrict__ out) {
    int idx = blockIdx.x * 256 + threadIdx.x;
    if (idx >= NB * KOC * HW * HW) return;
    int ow = idx % 56, t = idx / 56, oh = t % 56, t2 = t / 56, ko = t2 % 256, n = t2 / 256;
    float accv = bias[ko];
    for (int c = 0; c < CI; ++c)
        for (int r = 0; r < 3; ++r) {
            int ih = oh - 1 + r;
            if (ih < 0 || ih >= HW) continue;
            for (int s = 0; s < 3; ++s) {
                int iw = ow - 1 + s;
                if (iw < 0 || iw >= HW) continue;
                accv += x[((size_t)(n * CI + c) * HW + ih) * HW + iw] *
                        w[((size_t)(ko * CI + c) * 3 + r) * 3 + s];
            }
        }
    out[idx] = accv;
}

extern "C" void kernel_launch(void* const* d_in, const int* in_sizes, int n_in,
                              void* d_out, int out_size, void* d_ws, size_t ws_size,
                              hipStream_t stream) {
    const float* x    = (const float*)d_in[0];
    const float* w    = (const float*)d_in[1];
    const float* bias = (const float*)d_in[2];
    float* out = (float*)d_out;

    size_t need = XP_OFF_BYTES + XP_ELEMS * 2;
    if (ws_size < need) {
        int tot = NB * KOC * HW * HW;
        conv_naive<<<dim3((tot + 255) / 256), dim3(256), 0, stream>>>(x, w, bias, out);
        return;
    }

    ushort_t* wbp = (ushort_t*)d_ws;
    ushort_t* xpd = (ushort_t*)((char*)d_ws + XP_OFF_BYTES);

    border_zero<<<dim3((NB * 228 * 16 + 255) / 256), dim3(256), 0, stream>>>(xpd);
    wt_bf16<<<dim3((KOC * CI + 255) / 256), dim3(256), 0, stream>>>(w, wbp);
    pad_nhwc_bf16<<<dim3(NB * HW), dim3(256), 0, stream>>>(x, xpd);

    conv_mfma<<<dim3(MTOT / 256), dim3(512), 0, stream>>>(xpd, wbp, bias, out);
}

// Round 6
// 105.186 us; speedup vs baseline: 1.0223x; 1.0223x over previous
//
#include <hip/hip_runtime.h>

typedef int   v4i __attribute__((ext_vector_type(4)));
typedef float v4f __attribute__((ext_vector_type(4)));
typedef unsigned short ushort_t;

#define NB 32
#define CI 128
#define HW 56
#define KOC 256
#define HP 58
#define MTOT (NB*HW*HW)                  // 100352
#define XP_ELEMS ((size_t)NB*HP*HP*CI)   // 13778944
#define XP_OFF_BYTES ((size_t)1<<20)

__device__ __forceinline__ unsigned short f2bf(float f) {
    unsigned int u = __builtin_bit_cast(unsigned int, f);
    u += 0x7fffu + ((u >> 16) & 1u);   // round-to-nearest-even
    return (unsigned short)(u >> 16);
}

__device__ __forceinline__ void gload16(const void* g, void* l) {
    __builtin_amdgcn_global_load_lds(
        (const __attribute__((address_space(1))) void*)g,
        (__attribute__((address_space(3))) void*)l, 16, 0, 0);
}

// ---- weight (256,128,3,3) f32 -> Wb[rs][ko][c] bf16 (c contiguous)
__global__ void wt_bf16(const float* __restrict__ w, ushort_t* __restrict__ wb) {
    int t = blockIdx.x * 256 + threadIdx.x;      // t = ko*128 + c
    if (t >= KOC * CI) return;
    const float* src = w + (size_t)t * 9;
    int ko = t >> 7, c = t & 127;
    #pragma unroll
    for (int rs = 0; rs < 9; ++rs)
        wb[(size_t)(rs * KOC + ko) * CI + c] = f2bf(src[rs]);
}

// ---- x NCHW f32 -> padded NHWC bf16 Xp[n][58][58][128] (interior only)
__global__ void pad_nhwc_bf16(const float* __restrict__ x, ushort_t* __restrict__ xp) {
    __shared__ ushort_t tile[HW][136];
    int b = blockIdx.x;                          // n*56 + h
    int n = b / HW, h = b % HW;
    int tid = threadIdx.x;
    const float* xr = x + (size_t)n * CI * HW * HW + (size_t)h * HW;
    for (int idx = tid; idx < CI * HW; idx += 256) {
        int c = idx / HW, w = idx % HW;
        tile[w][c] = f2bf(xr[(size_t)c * (HW * HW) + w]);
    }
    __syncthreads();
    ushort_t* xpr = xp + ((size_t)(n * HP + (h + 1)) * HP + 1) * CI;
    for (int idx = tid; idx < (HW * CI) / 8; idx += 256) {
        int w = idx >> 4, c8 = (idx & 15) * 8;
        *reinterpret_cast<uint4*>(xpr + (size_t)w * CI + c8) =
            *reinterpret_cast<const uint4*>(&tile[w][c8]);
    }
}

// ---- zero only the padding border of Xp
__global__ void border_zero(ushort_t* __restrict__ xp) {
    int t = blockIdx.x * 256 + threadIdx.x;
    if (t >= NB * 228 * 16) return;
    int c16 = t & 15;
    int p = (t >> 4) % 228;
    int n = t / (228 * 16);
    int h, wc;
    if (p < 58)       { h = 0;               wc = p; }
    else if (p < 116) { h = 57;              wc = p - 58; }
    else { int q = p - 116; h = 1 + (q >> 1); wc = (q & 1) * 57; }
    size_t off = ((size_t)(n * HP + h) * HP + wc) * CI + (size_t)c16 * 8;
    uint4 z; z.x = z.y = z.z = z.w = 0u;
    *reinterpret_cast<uint4*>(xp + off) = z;
}

// ================= main conv: m97-exact structure =================
// 128(ko) x 128(m) tile, BK=32, 4 waves of 64x64, SINGLE-buffer 16 KB LDS,
// per K-step: 4x global_load_lds -> syncthreads -> 8 ds_read_b128 + 16 MFMA
// -> syncthreads. High occupancy (4 blocks/CU) supplies the overlap (m114).
// LDS plane [128 rows][32 e]; swizzle: slot = chunk ^ ((row>>1)&3), applied
// as inverse-swizzled GLOBAL source + swizzled ds_read (linear DMA dest).

__global__ __launch_bounds__(256, 4) void conv_mfma(
    const ushort_t* __restrict__ xp,
    const ushort_t* __restrict__ wb,
    const float* __restrict__ bias,
    float* __restrict__ out)
{
    __shared__ alignas(16) ushort_t sA[128 * 32];   // 8 KB, rows = 64 B
    __shared__ alignas(16) ushort_t sB[128 * 32];   // 8 KB

    const int tid  = threadIdx.x;
    const int lane = tid & 63;
    const int wv   = tid >> 6;          // 0..3
    const int wko  = wv >> 1, wm = wv & 1;           // 2x2 waves of 64x64
    // XCD-aware bijective swizzle: 1568 blocks = 8 XCDs x 196 contiguous
    const int bid   = blockIdx.x;
    const int chunk = (bid & 7) * 196 + (bid >> 3);
    const int mt = chunk >> 1, kt = chunk & 1;       // adjacent chunks share m-tile
    const int m0 = mt * 128, ko0 = kt * 128;
    const int lm = lane & 15, lk = lane >> 4;

    // ---- staging sources: instr q in {0,1} covers rows q*64 + wv*16 + (lane>>2)
    const int sc   = (lane & 3) ^ ((lane >> 3) & 3);  // inverse-swizzled 16B chunk
    const int row0 = wv * 16 + (lane >> 2);
    const size_t wS0 = (size_t)(ko0 + row0) * CI + sc * 8;
    const size_t wS1 = (size_t)(ko0 + 64 + row0) * CI + sc * 8;
    size_t xS0, xS1;
    {
        int mm = m0 + row0;
        int n = mm / 3136, tt = mm % 3136, oh = tt / 56, ow = tt % 56;
        xS0 = ((size_t)(n * HP + oh) * HP + ow) * CI + sc * 8;
        mm = m0 + 64 + row0;
        n = mm / 3136; tt = mm % 3136; oh = tt / 56; ow = tt % 56;
        xS1 = ((size_t)(n * HP + oh) * HP + ow) * CI + sc * 8;
    }

    // ---- fragment LDS offsets (elements): row*32 + (lk ^ ((row>>1)&3))*8
    int aoffE[4], boffE[4];
    #pragma unroll
    for (int a = 0; a < 4; ++a) {
        int row = wko * 64 + a * 16 + lm;
        aoffE[a] = row * 32 + (lk ^ ((row >> 1) & 3)) * 8;
    }
    #pragma unroll
    for (int b = 0; b < 4; ++b) {
        int row = wm * 64 + b * 16 + lm;
        boffE[b] = row * 32 + (lk ^ ((row >> 1) & 3)) * 8;
    }

    v4f acc[4][4];
    const v4f vzero = {0.f, 0.f, 0.f, 0.f};
    #pragma unroll
    for (int a = 0; a < 4; ++a)
        #pragma unroll
        for (int b = 0; b < 4; ++b) acc[a][b] = vzero;

    char* dA = (char*)sA + wv * 1024;
    char* dB = (char*)sB + wv * 1024;

    for (int it = 0; it < 36; ++it) {
        int rs = it >> 2, coff = (it & 3) * 32;
        int r  = (rs * 11) >> 5, s = rs - r * 3;     // rs/3, rs%3 for rs<9
        size_t woff = (size_t)rs * (KOC * CI) + coff;
        size_t xoff = (size_t)(r * HP + s) * CI + coff;

        gload16(wb + wS0 + woff, dA);
        gload16(wb + wS1 + woff, dA + 4096);
        gload16(xp + xS0 + xoff, dB);
        gload16(xp + xS1 + xoff, dB + 4096);
        __syncthreads();                              // vmcnt drain + barrier

        v4i af[4], bf[4];
        #pragma unroll
        for (int a = 0; a < 4; ++a)
            af[a] = *reinterpret_cast<const v4i*>(&sA[aoffE[a]]);
        #pragma unroll
        for (int b = 0; b < 4; ++b)
            bf[b] = *reinterpret_cast<const v4i*>(&sB[boffE[b]]);

        __builtin_amdgcn_s_setprio(1);
        #pragma unroll
        for (int a = 0; a < 4; ++a)
            #pragma unroll
            for (int b = 0; b < 4; ++b)
                asm volatile("v_mfma_f32_16x16x32_bf16 %0, %1, %2, %0"
                             : "+v"(acc[a][b]) : "v"(af[a]), "v"(bf[b]));
        __builtin_amdgcn_s_setprio(0);
        __syncthreads();                              // protect single buffer
    }

    // ---- MFMA->VALU hazard fence
    asm volatile("s_nop 7\n\ts_nop 7\n\ts_nop 7"
        : "+v"(acc[0][0]), "+v"(acc[0][1]), "+v"(acc[0][2]), "+v"(acc[0][3]),
          "+v"(acc[1][0]), "+v"(acc[1][1]), "+v"(acc[1][2]), "+v"(acc[1][3]),
          "+v"(acc[2][0]), "+v"(acc[2][1]), "+v"(acc[2][2]), "+v"(acc[2][3]),
          "+v"(acc[3][0]), "+v"(acc[3][1]), "+v"(acc[3][2]), "+v"(acc[3][3]));

    // ---- epilogue: D row=(lane>>4)*4+r -> ko ; col=lane&15 -> m
    const int koB = ko0 + wko * 64 + lk * 4;
    v4f bv[4];
    #pragma unroll
    for (int a = 0; a < 4; ++a)
        bv[a] = *reinterpret_cast<const v4f*>(bias + koB + a * 16);

    #pragma unroll
    for (int bb = 0; bb < 4; ++bb) {
        int mcol = m0 + wm * 64 + bb * 16 + lm;
        int n = mcol / 3136, t4 = mcol % 3136, oh = t4 / 56, ow = t4 % 56;
        size_t obase = (size_t)n * (KOC * 3136) + (size_t)oh * 56 + ow;
        #pragma unroll
        for (int a = 0; a < 4; ++a) {
            int kk = koB + a * 16;
            #pragma unroll
            for (int r = 0; r < 4; ++r)
                out[obase + (size_t)(kk + r) * 3136] = acc[a][bb][r] + bv[a][r];
        }
    }
}

// ---- insurance path if workspace is too small
__global__ void conv_naive(const float* __restrict__ x, const float* __restrict__ w,
                           const float* __restrict__ bias, float* __restrict__ out) {
    int idx = blockIdx.x * 256 + threadIdx.x;
    if (idx >= NB * KOC * HW * HW) return;
    int ow = idx % 56, t = idx / 56, oh = t % 56, t2 = t / 56, ko = t2 % 256, n = t2 / 256;
    float accv = bias[ko];
    for (int c = 0; c < CI; ++c)
        for (int r = 0; r < 3; ++r) {
            int ih = oh - 1 + r;
            if (ih < 0 || ih >= HW) continue;
            for (int s = 0; s < 3; ++s) {
                int iw = ow - 1 + s;
                if (iw < 0 || iw >= HW) continue;
                accv += x[((size_t)(n * CI + c) * HW + ih) * HW + iw] *
                        w[((size_t)(ko * CI + c) * 3 + r) * 3 + s];
            }
        }
    out[idx] = accv;
}

extern "C" void kernel_launch(void* const* d_in, const int* in_sizes, int n_in,
                              void* d_out, int out_size, void* d_ws, size_t ws_size,
                              hipStream_t stream) {
    const float* x    = (const float*)d_in[0];
    const float* w    = (const float*)d_in[1];
    const float* bias = (const float*)d_in[2];
    float* out = (float*)d_out;

    size_t need = XP_OFF_BYTES + XP_ELEMS * 2;
    if (ws_size < need) {
        int tot = NB * KOC * HW * HW;
        conv_naive<<<dim3((tot + 255) / 256), dim3(256), 0, stream>>>(x, w, bias, out);
        return;
    }

    ushort_t* wbp = (ushort_t*)d_ws;
    ushort_t* xpd = (ushort_t*)((char*)d_ws + XP_OFF_BYTES);

    border_zero<<<dim3((NB * 228 * 16 + 255) / 256), dim3(256), 0, stream>>>(xpd);
    wt_bf16<<<dim3((KOC * CI + 255) / 256), dim3(256), 0, stream>>>(w, wbp);
    pad_nhwc_bf16<<<dim3(NB * HW), dim3(256), 0, stream>>>(x, xpd);

    conv_mfma<<<dim3((MTOT / 128) * 2), dim3(256), 0, stream>>>(xpd, wbp, bias, out);
}